// Round 2
// baseline (753.191 us; speedup 1.0000x reference)
//
#include <hip/hip_runtime.h>
#include <hip/hip_bf16.h>
#include <hip/hip_fp16.h>

typedef __attribute__((ext_vector_type(4))) float f32x4;
typedef __attribute__((ext_vector_type(8))) __bf16 bf16x8;
typedef __attribute__((ext_vector_type(4))) __bf16 bf16x4;
typedef __attribute__((ext_vector_type(8))) _Float16 f16x8;

static __device__ __forceinline__ f32x4 mfma16(bf16x8 a, bf16x8 b, f32x4 c){
  return __builtin_amdgcn_mfma_f32_16x16x32_bf16(a, b, c, 0, 0, 0);
}

// ---------------- K1a: x f32 -> bf16 ----------------
__global__ __launch_bounds__(256) void k_cvt_x(const float* __restrict__ x, __bf16* __restrict__ xbf){
  int idx = (blockIdx.x*256 + threadIdx.x)*4;
  float4 v = *reinterpret_cast<const float4*>(x + idx);
  bf16x4 o; o[0]=(__bf16)v.x; o[1]=(__bf16)v.y; o[2]=(__bf16)v.z; o[3]=(__bf16)v.w;
  *reinterpret_cast<bf16x4*>(xbf + idx) = o;
}

// ---------------- K1b: Wqkv [512][1536] f32 -> WT [1536][512] bf16 ----------------
__global__ __launch_bounds__(256) void k_transpose_w(const float* __restrict__ W, __bf16* __restrict__ WT){
  __shared__ __align__(16) __bf16 tile[64*80];   // pad to 160B rows (16B aligned)
  int bn = blockIdx.x % 24, bk = blockIdx.x / 24;
  int n0 = bn*64, k0 = bk*64;
  int t = threadIdx.x;
#pragma unroll
  for (int r=0;r<4;r++){
    int k = r*16 + (t>>4), c4 = t&15;
    float4 v = *reinterpret_cast<const float4*>(W + (size_t)(k0+k)*1536 + n0 + c4*4);
    tile[(c4*4+0)*80 + k] = (__bf16)v.x;
    tile[(c4*4+1)*80 + k] = (__bf16)v.y;
    tile[(c4*4+2)*80 + k] = (__bf16)v.z;
    tile[(c4*4+3)*80 + k] = (__bf16)v.w;
  }
  __syncthreads();
#pragma unroll
  for (int r=0;r<2;r++){
    int idx = r*256 + t;
    int n = idx>>3, kc = idx&7;
    bf16x8 v = *reinterpret_cast<bf16x8*>(&tile[n*80 + kc*8]);
    *reinterpret_cast<bf16x8*>(WT + (size_t)(n0+n)*512 + k0 + kc*8) = v;
  }
}

// ---------------- K2: qkv = x@Wqkv + b, scatter to q/k/vT (bf16) ----------------
// grid 768 = (2048/64)*(1536/64); 256 thr = 4 waves, each wave 32x32
__global__ __launch_bounds__(256) void k_qkv(const __bf16* __restrict__ xbf, const __bf16* __restrict__ WT,
                                             const float* __restrict__ bias,
                                             __bf16* __restrict__ qbf, __bf16* __restrict__ kbf,
                                             __bf16* __restrict__ vT){
  int bid = blockIdx.x;
  int m0 = (bid/24)*64, n0 = (bid%24)*64;
  int t = threadIdx.x, w = t>>6, l = t&63;
  int wm = (w>>1)*32, wn = (w&1)*32;
  int r = l&15, q = l>>4;
  f32x4 acc00={0,0,0,0}, acc01={0,0,0,0}, acc10={0,0,0,0}, acc11={0,0,0,0};
  const __bf16* a0p = xbf + (size_t)(m0+wm+r)*512 + q*8;
  const __bf16* a1p = a0p + 16*512;
  const __bf16* b0p = WT + (size_t)(n0+wn+r)*512 + q*8;
  const __bf16* b1p = b0p + 16*512;
#pragma unroll
  for (int ks=0; ks<16; ks++){
    bf16x8 a0 = *reinterpret_cast<const bf16x8*>(a0p + ks*32);
    bf16x8 a1 = *reinterpret_cast<const bf16x8*>(a1p + ks*32);
    bf16x8 b0 = *reinterpret_cast<const bf16x8*>(b0p + ks*32);
    bf16x8 b1 = *reinterpret_cast<const bf16x8*>(b1p + ks*32);
    acc00 = mfma16(a0,b0,acc00);
    acc01 = mfma16(a0,b1,acc01);
    acc10 = mfma16(a1,b0,acc10);
    acc11 = mfma16(a1,b1,acc11);
  }
  f32x4 accs[2][2] = {{acc00,acc01},{acc10,acc11}};
#pragma unroll
  for (int mi=0;mi<2;mi++)
#pragma unroll
  for (int ni=0;ni<2;ni++){
#pragma unroll
    for (int e=0;e<4;e++){
      int row = m0 + wm + mi*16 + q*4 + e;
      int n   = n0 + wn + ni*16 + r;
      float v = accs[mi][ni][e] + bias[n];
      int bb = row>>9, s = row&511;
      int h = n/96, c = n - h*96;
      __bf16 bv = (__bf16)v;
      if (c < 32)       qbf[((size_t)(bb*16+h)*512 + s)*32 + c] = bv;
      else if (c < 64)  kbf[((size_t)(bb*16+h)*512 + s)*32 + (c-32)] = bv;
      else              vT[((size_t)(bb*16+h)*32 + (c-64))*512 + s] = bv;
    }
  }
}

// ---------------- K3: edge scores per (b,i), fold W' trick ----------------
// edge[b,h,i,j] = rq*ksum + rk*qsum (+bias terms), masked -> -30000, f16
__global__ __launch_bounds__(256) void k_edge(const float* __restrict__ p, const int* __restrict__ mask,
                                              const float* __restrict__ Wrqk, const float* __restrict__ brqk,
                                              const __bf16* __restrict__ qbf, const __bf16* __restrict__ kbf,
                                              _Float16* __restrict__ edge){
  __shared__ __align__(16) __bf16 P_lds[64*128];   // XOR-swizzled
  __shared__ __align__(16) __bf16 WT_lds[16*128];  // W'^T [h][e], XOR-swizzled
  __shared__ __align__(16) _Float16 sc[16*520];
  __shared__ int mask_lds[512];
  __shared__ float ksum_lds[16], qsum_lds[16], cst_lds[16];
  int bid = blockIdx.x; int b = bid>>9, i = bid&511;
  int t = threadIdx.x, w = t>>6, l = t&63;
  int r = l&15, q = l>>4;

  mask_lds[t]       = mask[(size_t)(b*512+i)*512 + t];
  mask_lds[256+t]   = mask[(size_t)(b*512+i)*512 + 256 + t];

  { // per-head ksum/qsum (+ brqk const) — 16 lanes per head
    int h = t>>4, dd = t&15;
    const __bf16* kp = kbf + ((size_t)(b*16+h)*512 + i)*32;
    const __bf16* qp = qbf + ((size_t)(b*16+h)*512 + i)*32;
    float kv = (float)kp[dd*2] + (float)kp[dd*2+1];
    float qv = (float)qp[dd*2] + (float)qp[dd*2+1];
#pragma unroll
    for (int m=1;m<16;m<<=1){ kv += __shfl_xor(kv,m); qv += __shfl_xor(qv,m); }
    if (dd==0){ ksum_lds[h]=kv; qsum_lds[h]=qv; cst_lds[h] = brqk[2*h]*kv + brqk[2*h+1]*qv; }
  }
  __syncthreads();
  { // fold: W'[e,h] = Wrqk[e,2h]*ksum + Wrqk[e,2h+1]*qsum, stored transposed [h][e]
    int idx = t*8; int h = idx>>7, e0 = idx&127;
    float ksm = ksum_lds[h], qsm = qsum_lds[h];
    bf16x8 wv;
#pragma unroll
    for (int u=0;u<8;u++)
      wv[u] = (__bf16)(Wrqk[(e0+u)*32 + 2*h]*ksm + Wrqk[(e0+u)*32 + 2*h+1]*qsm);
    int byte = (h*128 + e0)*2; byte ^= ((h&7)<<4);
    *reinterpret_cast<bf16x8*>(((char*)WT_lds) + byte) = wv;
  }
  __syncthreads();
  bf16x8 bfrag[4];
#pragma unroll
  for (int ks=0;ks<4;ks++){
    int byte = (r*128 + ks*32 + q*8)*2; byte ^= ((r&7)<<4);
    bfrag[ks] = *reinterpret_cast<bf16x8*>(((char*)WT_lds) + byte);
  }

  const float* prow = p + (size_t)(b*512+i)*65536;
  for (int jt=0; jt<8; jt++){
#pragma unroll
    for (int rr=0; rr<8; rr++){
      int idx = rr*256 + t;
      int row = idx>>5, c4 = idx&31;
      float4 v = *reinterpret_cast<const float4*>(prow + (size_t)(jt*64+row)*128 + c4*4);
      bf16x4 o; o[0]=(__bf16)v.x; o[1]=(__bf16)v.y; o[2]=(__bf16)v.z; o[3]=(__bf16)v.w;
      int byte = row*256 + c4*8; byte ^= ((row&7)<<4);
      *reinterpret_cast<bf16x4*>(((char*)P_lds) + byte) = o;
    }
    __syncthreads();
    f32x4 acc = {0,0,0,0};
#pragma unroll
    for (int ks=0;ks<4;ks++){
      int rrow = w*16 + r;
      int byte = (rrow*128 + ks*32 + q*8)*2; byte ^= ((rrow&7)<<4);
      bf16x8 afrag = *reinterpret_cast<bf16x8*>(((char*)P_lds) + byte);
      acc = mfma16(afrag, bfrag[ks], acc);
    }
#pragma unroll
    for (int e=0;e<4;e++){
      int j = jt*64 + w*16 + q*4 + e;          // D row = j-local
      float v = acc[e] + cst_lds[r];           // D col = h = l&15
      v = mask_lds[j] ? v : -30000.0f;
      sc[r*520 + j] = (_Float16)v;
    }
    __syncthreads();
  }
#pragma unroll
  for (int rr=0; rr<4; rr++){
    int idx = rr*256 + t;
    int h = idx>>6, c8 = idx&63;
    uint4 vv = *reinterpret_cast<uint4*>(&sc[h*520 + c8*8]);
    *reinterpret_cast<uint4*>(edge + ((size_t)(b*16+h)*512 + i)*512 + c8*8) = vv;
  }
}

// ---------------- K4: attention per (b,h,i-tile 64) ----------------
__global__ __launch_bounds__(256) void k_attn(const __bf16* __restrict__ qbf, const __bf16* __restrict__ kbf,
                                              const __bf16* __restrict__ vT, const _Float16* __restrict__ edge,
                                              float* __restrict__ out){
  __shared__ __align__(16) _Float16 sc[64*520];   // scores f16, then probs bf16 in-place
  __shared__ float rowsum[64];
  int bid = blockIdx.x;
  int b = bid>>7, h = (bid>>3)&15, i0 = (bid&7)*64;
  int t = threadIdx.x, w = t>>6, l = t&63;
  int iw = w*16, r = l&15, q = l>>4;
  size_t bh = (size_t)(b*16+h);
  const __bf16* qp = qbf + bh*512*32;
  const __bf16* kp = kbf + bh*512*32;
  const __bf16* vp = vT  + bh*32*512;
  const _Float16* ep = edge + (bh*512 + i0)*512;
  const float scale = 0.1020620726159658f;   // 1/sqrt(96)

  bf16x8 qfrag = *reinterpret_cast<const bf16x8*>(qp + (size_t)(i0+iw+r)*32 + q*8);
  for (int jt=0; jt<32; jt++){
    bf16x8 kfrag = *reinterpret_cast<const bf16x8*>(kp + (size_t)(jt*16+r)*32 + q*8);
    f32x4 acc = {0,0,0,0};
    acc = mfma16(qfrag, kfrag, acc);
#pragma unroll
    for (int e=0;e<4;e++){
      int ii = iw + q*4 + e;
      int j  = jt*16 + r;
      float s = (acc[e] + (float)ep[(size_t)ii*512 + j]) * scale;
      sc[ii*520 + j] = (_Float16)s;
    }
  }
  __syncthreads();
  { // softmax: lane owns row iw+r, quarter q of columns
    int row = iw + r;
    float mx = -3.0e38f;
#pragma unroll
    for (int k=0;k<16;k++){
      f16x8 vv = *reinterpret_cast<f16x8*>(((char*)sc) + (size_t)row*1040 + q*256 + k*16);
#pragma unroll
      for (int u=0;u<8;u++) mx = fmaxf(mx, (float)vv[u]);
    }
    mx = fmaxf(mx, __shfl_xor(mx,16));
    mx = fmaxf(mx, __shfl_xor(mx,32));
    float sum = 0.f;
#pragma unroll
    for (int k=0;k<16;k++){
      char* addr = ((char*)sc) + (size_t)row*1040 + q*256 + k*16;
      f16x8 sv = *reinterpret_cast<f16x8*>(addr);
      bf16x8 pv;
#pragma unroll
      for (int u=0;u<8;u++){
        float ee = __expf((float)sv[u] - mx);
        sum += ee;
        pv[u] = (__bf16)ee;
      }
      *reinterpret_cast<bf16x8*>(addr) = pv;
    }
    sum += __shfl_xor(sum,16);
    sum += __shfl_xor(sum,32);
    if (q==0) rowsum[row] = sum;
  }
  __syncthreads();
  f32x4 pacc0 = {0,0,0,0}, pacc1 = {0,0,0,0};
#pragma unroll
  for (int ks=0; ks<16; ks++){
    bf16x8 pfrag = *reinterpret_cast<bf16x8*>(((char*)sc) + (size_t)(iw+r)*1040 + ks*64 + q*16);
    bf16x8 v0 = *reinterpret_cast<const bf16x8*>(vp + (size_t)(0 +r)*512 + ks*32 + q*8);
    bf16x8 v1 = *reinterpret_cast<const bf16x8*>(vp + (size_t)(16+r)*512 + ks*32 + q*8);
    pacc0 = mfma16(pfrag, v0, pacc0);
    pacc1 = mfma16(pfrag, v1, pacc1);
  }
#pragma unroll
  for (int e=0;e<4;e++){
    int ii = iw + q*4 + e;
    float inv = 1.0f / rowsum[ii];
    out[((size_t)(b*512) + i0 + ii)*512 + h*32 +      r] = pacc0[e]*inv;
    out[((size_t)(b*512) + i0 + ii)*512 + h*32 + 16 + r] = pacc1[e]*inv;
  }
}

// ---------------- launch ----------------
extern "C" void kernel_launch(void* const* d_in, const int* in_sizes, int n_in,
                              void* d_out, int out_size, void* d_ws, size_t ws_size,
                              hipStream_t stream){
  const float* x    = (const float*)d_in[0];
  const float* p    = (const float*)d_in[1];
  const int*   mask = (const int*)d_in[2];
  const float* Wqkv = (const float*)d_in[3];
  const float* bqkv = (const float*)d_in[4];
  const float* Wrqk = (const float*)d_in[5];
  const float* brqk = (const float*)d_in[6];
  float* out = (float*)d_out;
  char* ws = (char*)d_ws;

  __bf16* xbf = (__bf16*)(ws + 0);                       // 2,097,152 B
  __bf16* WT  = (__bf16*)(ws + 2097152);                 // 1,572,864 B
  __bf16* qbf = (__bf16*)(ws + 3670016);                 // 2,097,152 B
  __bf16* kbf = (__bf16*)(ws + 5767168);                 // 2,097,152 B
  __bf16* vT  = (__bf16*)(ws + 7864320);                 // 2,097,152 B
  _Float16* edge = (_Float16*)(ws + 9961472);            // 33,554,432 B  (total ~41.5 MB)

  k_cvt_x<<<dim3(1024), dim3(256), 0, stream>>>(x, xbf);
  k_transpose_w<<<dim3(192), dim3(256), 0, stream>>>(Wqkv, WT);
  k_qkv<<<dim3(768), dim3(256), 0, stream>>>(xbf, WT, bqkv, qbf, kbf, vT);
  k_edge<<<dim3(2048), dim3(256), 0, stream>>>(p, mask, Wrqk, brqk, qbf, kbf, edge);
  k_attn<<<dim3(512), dim3(256), 0, stream>>>(qbf, kbf, vT, edge, out);
}

// Round 3
// 751.780 us; speedup vs baseline: 1.0019x; 1.0019x over previous
//
#include <hip/hip_runtime.h>
#include <hip/hip_bf16.h>
#include <hip/hip_fp16.h>

typedef __attribute__((ext_vector_type(4))) float f32x4;
typedef __attribute__((ext_vector_type(8))) __bf16 bf16x8;
typedef __attribute__((ext_vector_type(4))) __bf16 bf16x4;
typedef __attribute__((ext_vector_type(8))) _Float16 f16x8;

static __device__ __forceinline__ f32x4 mfma16(bf16x8 a, bf16x8 b, f32x4 c){
  return __builtin_amdgcn_mfma_f32_16x16x32_bf16(a, b, c, 0, 0, 0);
}

// ---------------- K1a: x f32 -> bf16 ----------------
__global__ __launch_bounds__(256) void k_cvt_x(const float* __restrict__ x, __bf16* __restrict__ xbf){
  int idx = (blockIdx.x*256 + threadIdx.x)*4;
  float4 v = *reinterpret_cast<const float4*>(x + idx);
  bf16x4 o; o[0]=(__bf16)v.x; o[1]=(__bf16)v.y; o[2]=(__bf16)v.z; o[3]=(__bf16)v.w;
  *reinterpret_cast<bf16x4*>(xbf + idx) = o;
}

// ---------------- K1b: Wqkv [512][1536] f32 -> WT [1536][512] bf16 ----------------
__global__ __launch_bounds__(256) void k_transpose_w(const float* __restrict__ W, __bf16* __restrict__ WT){
  __shared__ __align__(16) __bf16 tile[64*80];   // pad to 160B rows (16B aligned)
  int bn = blockIdx.x % 24, bk = blockIdx.x / 24;
  int n0 = bn*64, k0 = bk*64;
  int t = threadIdx.x;
#pragma unroll
  for (int r=0;r<4;r++){
    int k = r*16 + (t>>4), c4 = t&15;
    float4 v = *reinterpret_cast<const float4*>(W + (size_t)(k0+k)*1536 + n0 + c4*4);
    tile[(c4*4+0)*80 + k] = (__bf16)v.x;
    tile[(c4*4+1)*80 + k] = (__bf16)v.y;
    tile[(c4*4+2)*80 + k] = (__bf16)v.z;
    tile[(c4*4+3)*80 + k] = (__bf16)v.w;
  }
  __syncthreads();
#pragma unroll
  for (int r=0;r<2;r++){
    int idx = r*256 + t;
    int n = idx>>3, kc = idx&7;
    bf16x8 v = *reinterpret_cast<bf16x8*>(&tile[n*80 + kc*8]);
    *reinterpret_cast<bf16x8*>(WT + (size_t)(n0+n)*512 + k0 + kc*8) = v;
  }
}

// ---------------- K2: qkv = x@Wqkv + b, scatter to q/k/vT (bf16) ----------------
__global__ __launch_bounds__(256) void k_qkv(const __bf16* __restrict__ xbf, const __bf16* __restrict__ WT,
                                             const float* __restrict__ bias,
                                             __bf16* __restrict__ qbf, __bf16* __restrict__ kbf,
                                             __bf16* __restrict__ vT){
  int bid = blockIdx.x;
  int m0 = (bid/24)*64, n0 = (bid%24)*64;
  int t = threadIdx.x, w = t>>6, l = t&63;
  int wm = (w>>1)*32, wn = (w&1)*32;
  int r = l&15, q = l>>4;
  f32x4 acc00={0,0,0,0}, acc01={0,0,0,0}, acc10={0,0,0,0}, acc11={0,0,0,0};
  const __bf16* a0p = xbf + (size_t)(m0+wm+r)*512 + q*8;
  const __bf16* a1p = a0p + 16*512;
  const __bf16* b0p = WT + (size_t)(n0+wn+r)*512 + q*8;
  const __bf16* b1p = b0p + 16*512;
#pragma unroll
  for (int ks=0; ks<16; ks++){
    bf16x8 a0 = *reinterpret_cast<const bf16x8*>(a0p + ks*32);
    bf16x8 a1 = *reinterpret_cast<const bf16x8*>(a1p + ks*32);
    bf16x8 b0 = *reinterpret_cast<const bf16x8*>(b0p + ks*32);
    bf16x8 b1 = *reinterpret_cast<const bf16x8*>(b1p + ks*32);
    acc00 = mfma16(a0,b0,acc00);
    acc01 = mfma16(a0,b1,acc01);
    acc10 = mfma16(a1,b0,acc10);
    acc11 = mfma16(a1,b1,acc11);
  }
  f32x4 accs[2][2] = {{acc00,acc01},{acc10,acc11}};
#pragma unroll
  for (int mi=0;mi<2;mi++)
#pragma unroll
  for (int ni=0;ni<2;ni++){
#pragma unroll
    for (int e=0;e<4;e++){
      int row = m0 + wm + mi*16 + q*4 + e;
      int n   = n0 + wn + ni*16 + r;
      float v = accs[mi][ni][e] + bias[n];
      int bb = row>>9, s = row&511;
      int h = n/96, c = n - h*96;
      __bf16 bv = (__bf16)v;
      if (c < 32)       qbf[((size_t)(bb*16+h)*512 + s)*32 + c] = bv;
      else if (c < 64)  kbf[((size_t)(bb*16+h)*512 + s)*32 + (c-32)] = bv;
      else              vT[((size_t)(bb*16+h)*32 + (c-64))*512 + s] = bv;
    }
  }
}

// ---------------- K3: edge scores per (b,i) — direct global->reg streaming ----------------
// edge[b,h,i,j] = rq*ksum + rk*qsum (+bias consts), masked -> -30000, f16.
// No LDS staging of p: each lane loads its own MFMA A-fragment (2x float4),
// converts f32->bf16 in registers. No barriers in the main loop (waves own
// disjoint sc rows); single barrier before the coalesced write-out.
__global__ __launch_bounds__(256) void k_edge(const float* __restrict__ p, const int* __restrict__ mask,
                                              const float* __restrict__ Wrqk, const float* __restrict__ brqk,
                                              const __bf16* __restrict__ qbf, const __bf16* __restrict__ kbf,
                                              _Float16* __restrict__ edge){
  __shared__ __align__(16) __bf16 WT_lds[16*128];  // W'^T [h][e], XOR-swizzled
  __shared__ __align__(16) _Float16 sc[16*520];
  __shared__ int mask_lds[512];
  __shared__ float ksum_lds[16], qsum_lds[16], cst_lds[16];
  int bid = blockIdx.x; int b = bid>>9, i = bid&511;
  int t = threadIdx.x, w = t>>6, l = t&63;
  int r = l&15, q = l>>4;

  mask_lds[t]       = mask[(size_t)(b*512+i)*512 + t];
  mask_lds[256+t]   = mask[(size_t)(b*512+i)*512 + 256 + t];

  { // per-head ksum/qsum (+ brqk const) — 16 lanes per head
    int h = t>>4, dd = t&15;
    const __bf16* kp = kbf + ((size_t)(b*16+h)*512 + i)*32;
    const __bf16* qp = qbf + ((size_t)(b*16+h)*512 + i)*32;
    float kv = (float)kp[dd*2] + (float)kp[dd*2+1];
    float qv = (float)qp[dd*2] + (float)qp[dd*2+1];
#pragma unroll
    for (int m=1;m<16;m<<=1){ kv += __shfl_xor(kv,m); qv += __shfl_xor(qv,m); }
    if (dd==0){ ksum_lds[h]=kv; qsum_lds[h]=qv; cst_lds[h] = brqk[2*h]*kv + brqk[2*h+1]*qv; }
  }
  __syncthreads();
  { // fold: W'[e,h] = Wrqk[e,2h]*ksum + Wrqk[e,2h+1]*qsum, stored transposed [h][e]
    int idx = t*8; int h = idx>>7, e0 = idx&127;
    float ksm = ksum_lds[h], qsm = qsum_lds[h];
    bf16x8 wv;
#pragma unroll
    for (int u=0;u<8;u++)
      wv[u] = (__bf16)(Wrqk[(e0+u)*32 + 2*h]*ksm + Wrqk[(e0+u)*32 + 2*h+1]*qsm);
    int byte = (h*128 + e0)*2; byte ^= ((h&7)<<4);
    *reinterpret_cast<bf16x8*>(((char*)WT_lds) + byte) = wv;
  }
  __syncthreads();
  bf16x8 bfrag[4];
#pragma unroll
  for (int ks=0;ks<4;ks++){
    int byte = (r*128 + ks*32 + q*8)*2; byte ^= ((r&7)<<4);
    bfrag[ks] = *reinterpret_cast<bf16x8*>(((char*)WT_lds) + byte);
  }

  // lane's A-fragment base: row (w*16+r) within each 64-row tile, cols q*8..q*8+7 per ks
  const float* prow = p + (size_t)(b*512+i)*65536 + (size_t)(w*16+r)*128 + q*8;
  for (int jt=0; jt<8; jt++){
    const float* pj = prow + (size_t)jt*64*128;
    f32x4 v[8];
#pragma unroll
    for (int ks=0; ks<4; ks++){
      v[2*ks]   = *reinterpret_cast<const f32x4*>(pj + ks*32);
      v[2*ks+1] = *reinterpret_cast<const f32x4*>(pj + ks*32 + 4);
    }
    f32x4 acc = {0,0,0,0};
#pragma unroll
    for (int ks=0; ks<4; ks++){
      bf16x8 a;
      a[0]=(__bf16)v[2*ks][0]; a[1]=(__bf16)v[2*ks][1];
      a[2]=(__bf16)v[2*ks][2]; a[3]=(__bf16)v[2*ks][3];
      a[4]=(__bf16)v[2*ks+1][0]; a[5]=(__bf16)v[2*ks+1][1];
      a[6]=(__bf16)v[2*ks+1][2]; a[7]=(__bf16)v[2*ks+1][3];
      acc = mfma16(a, bfrag[ks], acc);
    }
#pragma unroll
    for (int e=0;e<4;e++){
      int j = jt*64 + w*16 + q*4 + e;          // D row = j-local
      float vv = acc[e] + cst_lds[r];          // D col = h = l&15
      vv = mask_lds[j] ? vv : -30000.0f;
      sc[r*520 + j] = (_Float16)vv;
    }
  }
  __syncthreads();
#pragma unroll
  for (int rr=0; rr<4; rr++){
    int idx = rr*256 + t;
    int h = idx>>6, c8 = idx&63;
    uint4 vv = *reinterpret_cast<uint4*>(&sc[h*520 + c8*8]);
    *reinterpret_cast<uint4*>(edge + ((size_t)(b*16+h)*512 + i)*512 + c8*8) = vv;
  }
}

// ---------------- K4: attention per (b,h,i-tile 64) ----------------
__global__ __launch_bounds__(256) void k_attn(const __bf16* __restrict__ qbf, const __bf16* __restrict__ kbf,
                                              const __bf16* __restrict__ vT, const _Float16* __restrict__ edge,
                                              float* __restrict__ out){
  __shared__ __align__(16) _Float16 sc[64*520];   // scores f16, then probs bf16 in-place
  __shared__ float rowsum[64];
  int bid = blockIdx.x;
  int b = bid>>7, h = (bid>>3)&15, i0 = (bid&7)*64;
  int t = threadIdx.x, w = t>>6, l = t&63;
  int iw = w*16, r = l&15, q = l>>4;
  size_t bh = (size_t)(b*16+h);
  const __bf16* qp = qbf + bh*512*32;
  const __bf16* kp = kbf + bh*512*32;
  const __bf16* vp = vT  + bh*32*512;
  const _Float16* ep = edge + (bh*512 + i0)*512;
  const float scale = 0.1020620726159658f;   // 1/sqrt(96)

  bf16x8 qfrag = *reinterpret_cast<const bf16x8*>(qp + (size_t)(i0+iw+r)*32 + q*8);
  for (int jt=0; jt<32; jt++){
    bf16x8 kfrag = *reinterpret_cast<const bf16x8*>(kp + (size_t)(jt*16+r)*32 + q*8);
    f32x4 acc = {0,0,0,0};
    acc = mfma16(qfrag, kfrag, acc);
#pragma unroll
    for (int e=0;e<4;e++){
      int ii = iw + q*4 + e;
      int j  = jt*16 + r;
      float s = (acc[e] + (float)ep[(size_t)ii*512 + j]) * scale;
      sc[ii*520 + j] = (_Float16)s;
    }
  }
  __syncthreads();
  { // softmax: lane owns row iw+r, quarter q of columns
    int row = iw + r;
    float mx = -3.0e38f;
#pragma unroll
    for (int k=0;k<16;k++){
      f16x8 vv = *reinterpret_cast<f16x8*>(((char*)sc) + (size_t)row*1040 + q*256 + k*16);
#pragma unroll
      for (int u=0;u<8;u++) mx = fmaxf(mx, (float)vv[u]);
    }
    mx = fmaxf(mx, __shfl_xor(mx,16));
    mx = fmaxf(mx, __shfl_xor(mx,32));
    float sum = 0.f;
#pragma unroll
    for (int k=0;k<16;k++){
      char* addr = ((char*)sc) + (size_t)row*1040 + q*256 + k*16;
      f16x8 sv = *reinterpret_cast<f16x8*>(addr);
      bf16x8 pv;
#pragma unroll
      for (int u=0;u<8;u++){
        float ee = __expf((float)sv[u] - mx);
        sum += ee;
        pv[u] = (__bf16)ee;
      }
      *reinterpret_cast<bf16x8*>(addr) = pv;
    }
    sum += __shfl_xor(sum,16);
    sum += __shfl_xor(sum,32);
    if (q==0) rowsum[row] = sum;
  }
  __syncthreads();
  f32x4 pacc0 = {0,0,0,0}, pacc1 = {0,0,0,0};
#pragma unroll
  for (int ks=0; ks<16; ks++){
    bf16x8 pfrag = *reinterpret_cast<bf16x8*>(((char*)sc) + (size_t)(iw+r)*1040 + ks*64 + q*16);
    bf16x8 v0 = *reinterpret_cast<const bf16x8*>(vp + (size_t)(0 +r)*512 + ks*32 + q*8);
    bf16x8 v1 = *reinterpret_cast<const bf16x8*>(vp + (size_t)(16+r)*512 + ks*32 + q*8);
    pacc0 = mfma16(pfrag, v0, pacc0);
    pacc1 = mfma16(pfrag, v1, pacc1);
  }
#pragma unroll
  for (int e=0;e<4;e++){
    int ii = iw + q*4 + e;
    float inv = 1.0f / rowsum[ii];
    out[((size_t)(b*512) + i0 + ii)*512 + h*32 +      r] = pacc0[e]*inv;
    out[((size_t)(b*512) + i0 + ii)*512 + h*32 + 16 + r] = pacc1[e]*inv;
  }
}

// ---------------- launch ----------------
extern "C" void kernel_launch(void* const* d_in, const int* in_sizes, int n_in,
                              void* d_out, int out_size, void* d_ws, size_t ws_size,
                              hipStream_t stream){
  const float* x    = (const float*)d_in[0];
  const float* p    = (const float*)d_in[1];
  const int*   mask = (const int*)d_in[2];
  const float* Wqkv = (const float*)d_in[3];
  const float* bqkv = (const float*)d_in[4];
  const float* Wrqk = (const float*)d_in[5];
  const float* brqk = (const float*)d_in[6];
  float* out = (float*)d_out;
  char* ws = (char*)d_ws;

  __bf16* xbf = (__bf16*)(ws + 0);                       // 2,097,152 B
  __bf16* WT  = (__bf16*)(ws + 2097152);                 // 1,572,864 B
  __bf16* qbf = (__bf16*)(ws + 3670016);                 // 2,097,152 B
  __bf16* kbf = (__bf16*)(ws + 5767168);                 // 2,097,152 B
  __bf16* vT  = (__bf16*)(ws + 7864320);                 // 2,097,152 B
  _Float16* edge = (_Float16*)(ws + 9961472);            // 33,554,432 B  (total ~41.5 MB)

  k_cvt_x<<<dim3(1024), dim3(256), 0, stream>>>(x, xbf);
  k_transpose_w<<<dim3(192), dim3(256), 0, stream>>>(Wqkv, WT);
  k_qkv<<<dim3(768), dim3(256), 0, stream>>>(xbf, WT, bqkv, qbf, kbf, vT);
  k_edge<<<dim3(2048), dim3(256), 0, stream>>>(p, mask, Wrqk, brqk, qbf, kbf, edge);
  k_attn<<<dim3(512), dim3(256), 0, stream>>>(qbf, kbf, vT, edge, out);
}